// Round 3
// baseline (2303.364 us; speedup 1.0000x reference)
//
#include <hip/hip_runtime.h>
#include <hip/hip_cooperative_groups.h>
#include <math.h>

namespace cg = cooperative_groups;

#define KDIM 65536
#define MATF 262144           // 512*512 floats
#define EPSG 1e-6

using bf16x8 = __attribute__((ext_vector_type(8))) __bf16;
using f32x4  = __attribute__((ext_vector_type(4))) float;

// ---- ws layout (bytes) ----
// 4096   : double S[16]    (0:n2A 1:n2B 2:trA 3:trB 4:cross)
// 4224   : double Msum[1024]  (row sums; rows 0..511 input, 512..1023 target)
// 16384  : float G[2*MATF]                        (2 MB)
// 16384+2M: "big": Gp[2*nk*MATF] partials (dead after k_gfin), then reused:
//          Y0 Z0 Y1 Z1 (2 MB each) + W (4 MB) = 12 MB

__device__ __forceinline__ void cvt8(float4 a, float4 b, bf16x8& hi, bf16x8& lo) {
  float f[8] = {a.x, a.y, a.z, a.w, b.x, b.y, b.z, b.w};
#pragma unroll
  for (int e = 0; e < 8; ++e) {
    __bf16 h = (__bf16)f[e];
    hi[e] = h;
    lo[e] = (__bf16)(f[e] - (float)h);
  }
}

// Raw X X^T partials via bf16 split-3 MFMA. 128x128 upper-tri tiles (10),
// split-K nk chunks. grid (10, nk, 2). Diag tiles also accumulate fp64 row
// sums into Msum (replaces a dedicated means pass: -537 MB HBM traffic).
// Register-prefetch of next K-slab overlaps HBM latency with the MFMA block.
__global__ __launch_bounds__(256, 2) void k_gram(const float* __restrict__ X,
                                                 const float* __restrict__ Xt,
                                                 float* __restrict__ Gp,
                                                 double* __restrict__ Msum,
                                                 int nk, int chunk) {
  int rem = blockIdx.x, ti = 0;
  while (rem >= 4 - ti) { rem -= 4 - ti; ++ti; }
  const int tj = ti + rem;
  const int chunkIdx = blockIdx.y, inp = blockIdx.z;
  const float* __restrict__ A = inp ? Xt : X;
  float* __restrict__ C = Gp + ((size_t)(inp * nk + chunkIdx)) * MATF;
  const bool diag = (ti == tj);

  __shared__ bf16x8 AhV[512], AlV[512], BhV[512], BlV[512];   // 8 KB each

  const int t = threadIdx.x;
  const int srow = t & 127, skh = t >> 7;
  const int sbase = ((srow >> 4) << 6) + (skh << 5) + (srow & 15);

  const float* pa = A + (size_t)(ti * 128 + srow) * KDIM + (size_t)chunkIdx * chunk + skh * 16;
  const float* pb = A + (size_t)(tj * 128 + srow) * KDIM + (size_t)chunkIdx * chunk + skh * 16;

  const int wave = t >> 6, lane = t & 63;
  const int wy = (wave >> 1) * 64, wx = (wave & 1) * 64;

  f32x4 acc[4][4];
#pragma unroll
  for (int i = 0; i < 4; ++i)
#pragma unroll
    for (int j = 0; j < 4; ++j) acc[i][j] = (f32x4){0.f, 0.f, 0.f, 0.f};

  float4 ra0 = *(const float4*)(pa);
  float4 ra1 = *(const float4*)(pa + 4);
  float4 ra2 = *(const float4*)(pa + 8);
  float4 ra3 = *(const float4*)(pa + 12);
  float4 rb0, rb1, rb2, rb3;
  if (!diag) {
    rb0 = *(const float4*)(pb);
    rb1 = *(const float4*)(pb + 4);
    rb2 = *(const float4*)(pb + 8);
    rb3 = *(const float4*)(pb + 12);
  }
  float rsum = 0.f;

  for (int ks = 0; ks < chunk; ks += 32) {
    {
      bf16x8 h, l;
      cvt8(ra0, ra1, h, l); AhV[sbase] = h; AlV[sbase] = l;
      cvt8(ra2, ra3, h, l); AhV[sbase + 16] = h; AlV[sbase + 16] = l;
      if (diag) {
        rsum += ra0.x + ra0.y + ra0.z + ra0.w + ra1.x + ra1.y + ra1.z + ra1.w +
                ra2.x + ra2.y + ra2.z + ra2.w + ra3.x + ra3.y + ra3.z + ra3.w;
      } else {
        cvt8(rb0, rb1, h, l); BhV[sbase] = h; BlV[sbase] = l;
        cvt8(rb2, rb3, h, l); BhV[sbase + 16] = h; BlV[sbase + 16] = l;
      }
    }
    __syncthreads();
    if (ks + 32 < chunk) {      // prefetch next slab; consumed next iteration
      ra0 = *(const float4*)(pa + ks + 32);
      ra1 = *(const float4*)(pa + ks + 36);
      ra2 = *(const float4*)(pa + ks + 40);
      ra3 = *(const float4*)(pa + ks + 44);
      if (!diag) {
        rb0 = *(const float4*)(pb + ks + 32);
        rb1 = *(const float4*)(pb + ks + 36);
        rb2 = *(const float4*)(pb + ks + 40);
        rb3 = *(const float4*)(pb + ks + 44);
      }
    }
    const bf16x8* __restrict__ Bh = diag ? AhV : BhV;
    const bf16x8* __restrict__ Bl = diag ? AlV : BlV;
    bf16x8 ah[4], al[4], bh[4], bl[4];
#pragma unroll
    for (int g = 0; g < 4; ++g) {
      ah[g] = AhV[((wave >> 1) * 4 + g) * 64 + lane];
      al[g] = AlV[((wave >> 1) * 4 + g) * 64 + lane];
      bh[g] = Bh[((wave & 1) * 4 + g) * 64 + lane];
      bl[g] = Bl[((wave & 1) * 4 + g) * 64 + lane];
    }
#pragma unroll
    for (int i = 0; i < 4; ++i)
#pragma unroll
      for (int j = 0; j < 4; ++j) {
        acc[i][j] = __builtin_amdgcn_mfma_f32_16x16x32_bf16(ah[i], bh[j], acc[i][j], 0, 0, 0);
        acc[i][j] = __builtin_amdgcn_mfma_f32_16x16x32_bf16(al[i], bh[j], acc[i][j], 0, 0, 0);
        acc[i][j] = __builtin_amdgcn_mfma_f32_16x16x32_bf16(ah[i], bl[j], acc[i][j], 0, 0, 0);
      }
    __syncthreads();
  }
  if (diag) atomicAdd(&Msum[inp * 512 + ti * 128 + srow], (double)rsum);
  const int r4 = (lane >> 4) * 4, fc = lane & 15;
#pragma unroll
  for (int i = 0; i < 4; ++i) {
    const int grow = ti * 128 + wy + i * 16 + r4;
#pragma unroll
    for (int j = 0; j < 4; ++j) {
      const int gcol = tj * 128 + wx + j * 16 + fc;
#pragma unroll
      for (int r = 0; r < 4; ++r)
        C[(size_t)(grow + r) * 512 + gcol] = acc[i][j][r];
    }
  }
}

// Reduce nk partials (fp64), mean-correct with Msum, +eps on diag, /K.
// Mirror to lower tri; accumulate ||G||_F^2 and trace in fp64.
__global__ __launch_bounds__(256) void k_gfin(const float* __restrict__ Gp,
                                              const double* __restrict__ Msum,
                                              float* __restrict__ G,
                                              double* __restrict__ S, int nk) {
  const int inp = blockIdx.y;
  const int idx = blockIdx.x * 256 + threadIdx.x;
  const int i = idx >> 9, j = idx & 511;
  double n2 = 0.0, tr = 0.0;
  float* g = G + (size_t)inp * MATF;
  if (i <= j) {
    double sum = 0.0;
    const float* p = Gp + (size_t)inp * nk * MATF + idx;
    for (int c = 0; c < nk; ++c) sum += (double)p[(size_t)c * MATF];
    sum -= Msum[inp * 512 + i] * Msum[inp * 512 + j] * (1.0 / 65536.0);
    if (i == j) sum += EPSG;
    float v = (float)(sum * (1.0 / 65536.0));
    g[idx] = v;
    if (i < j) { g[(size_t)j * 512 + i] = v; n2 = 2.0 * (double)v * (double)v; }
    else       { n2 = (double)v * (double)v; tr = (double)v; }
  }
  __shared__ double s1[256], s2[256];
  s1[threadIdx.x] = n2; s2[threadIdx.x] = tr;
  __syncthreads();
  for (int o = 128; o > 0; o >>= 1) {
    if (threadIdx.x < o) { s1[threadIdx.x] += s1[threadIdx.x + o]; s2[threadIdx.x] += s2[threadIdx.x + o]; }
    __syncthreads();
  }
  if (threadIdx.x == 0) { atomicAdd(&S[inp], s1[0]); atomicAdd(&S[2 + inp], s2[0]); }
}

// 64x64-tile fp32 GEMM over K=[k0,k0+klen). A/B optionally sum of 2 partials.
// mode 0: C = acc ; mode 1: C = 1.5*E - 0.5*acc
__device__ __forceinline__ void gemm64(const float* __restrict__ A0, const float* __restrict__ A1,
                                       const float* __restrict__ B0, const float* __restrict__ B1,
                                       const float* __restrict__ E, float* __restrict__ C,
                                       float (*As)[68], float (*Bs)[68],
                                       int ti, int tj, int k0, int klen, int mode) {
  const int t = threadIdx.x;
  const int tx = t & 15, ty = t >> 4;
  const int ar = t & 63, akq = t >> 6;          // A stage: row, k-quarter
  const int bkr = t >> 2, bcs = (t & 3) << 4;   // B stage: k-row, col-seg

  const float* pa0 = A0 + (size_t)(ti * 64 + ar) * 512 + k0 + akq * 16;
  const float* pa1 = A1 ? A1 + (size_t)(ti * 64 + ar) * 512 + k0 + akq * 16 : nullptr;
  const float* pb0 = B0 + (size_t)(k0 + bkr) * 512 + tj * 64 + bcs;
  const float* pb1 = B1 ? B1 + (size_t)(k0 + bkr) * 512 + tj * 64 + bcs : nullptr;

  float acc[4][4] = {};
  for (int ks = 0; ks < klen; ks += 64) {
#pragma unroll
    for (int q = 0; q < 4; ++q) {
      float4 va = *(const float4*)(pa0 + ks + q * 4);
      if (pa1) {
        float4 vb = *(const float4*)(pa1 + ks + q * 4);
        va.x += vb.x; va.y += vb.y; va.z += vb.z; va.w += vb.w;
      }
      const int kk = akq * 16 + q * 4;
      As[kk + 0][ar] = va.x; As[kk + 1][ar] = va.y;
      As[kk + 2][ar] = va.z; As[kk + 3][ar] = va.w;
    }
#pragma unroll
    for (int q = 0; q < 4; ++q) {
      float4 va = *(const float4*)(pb0 + (size_t)ks * 512 + q * 4);
      if (pb1) {
        float4 vb = *(const float4*)(pb1 + (size_t)ks * 512 + q * 4);
        va.x += vb.x; va.y += vb.y; va.z += vb.z; va.w += vb.w;
      }
      *(float4*)&Bs[bkr][bcs + q * 4] = va;
    }
    __syncthreads();
#pragma unroll 16
    for (int kk = 0; kk < 64; ++kk) {
      const float4 av = *(const float4*)&As[kk][ty << 2];
      const float4 bv = *(const float4*)&Bs[kk][tx << 2];
      acc[0][0] += av.x * bv.x; acc[0][1] += av.x * bv.y; acc[0][2] += av.x * bv.z; acc[0][3] += av.x * bv.w;
      acc[1][0] += av.y * bv.x; acc[1][1] += av.y * bv.y; acc[1][2] += av.y * bv.z; acc[1][3] += av.y * bv.w;
      acc[2][0] += av.z * bv.x; acc[2][1] += av.z * bv.y; acc[2][2] += av.z * bv.z; acc[2][3] += av.z * bv.w;
      acc[3][0] += av.w * bv.x; acc[3][1] += av.w * bv.y; acc[3][2] += av.w * bv.z; acc[3][3] += av.w * bv.w;
    }
    __syncthreads();
  }
#pragma unroll
  for (int r = 0; r < 4; ++r) {
    const int row = ti * 64 + (ty << 2) + r;
    const size_t off = (size_t)row * 512 + tj * 64 + (tx << 2);
    float4 v = make_float4(acc[r][0], acc[r][1], acc[r][2], acc[r][3]);
    if (mode == 1) {
      float4 e = *(const float4*)(E + off);
      v.x = 1.5f * e.x - 0.5f * v.x; v.y = 1.5f * e.y - 0.5f * v.y;
      v.z = 1.5f * e.z - 0.5f * v.z; v.w = 1.5f * e.w - 0.5f * v.w;
    }
    *(float4*)&C[off] = v;
  }
}

// One cooperative kernel: NS init, 15 iterations (W=Z@Y split-K=2, then
// Yn=1.5Y-0.5*Y@W and Zn=1.5Z-0.5*W@Z), cross-trace, final loss.
// 256 blocks exactly: W phase  = mat(2) x part(2) x 64 tiles,
//                     YZ phase = mat(2) x {Y,Z}(2) x 64 tiles.
__global__ __launch_bounds__(256) void k_ns_all(const float* __restrict__ G,
                                                const double* __restrict__ Msum,
                                                double* __restrict__ S,
                                                float* __restrict__ Y0, float* __restrict__ Z0,
                                                float* __restrict__ Y1, float* __restrict__ Z1,
                                                float* __restrict__ W,
                                                float* __restrict__ out) {
  cg::grid_group grid = cg::this_grid();
  __shared__ __align__(16) float As[64][68];
  __shared__ __align__(16) float Bs[64][68];
  __shared__ double sm[256];
  const int bid = blockIdx.x, t = threadIdx.x;

  {
    const float normA = (float)sqrt(S[0]);
    const float normB = (float)sqrt(S[1]);
#pragma unroll
    for (int c = 0; c < 8; ++c) {
      const int idx = c * 65536 + bid * 256 + t;
      const float nrm = (idx >> 18) ? normB : normA;
      const int loc = idx & (MATF - 1);
      Y0[idx] = G[idx] / nrm;
      Z0[idx] = ((loc >> 9) == (loc & 511)) ? 1.0f : 0.0f;
    }
  }
  grid.sync();

  float *Yc = Y0, *Zc = Z0, *Yn = Y1, *Zn = Z1;
  const int mat = bid >> 7;
  const int sub = (bid >> 6) & 1;
  const int tile = bid & 63, ti = tile >> 3, tj = tile & 7;
  const size_t mo = (size_t)mat * MATF;

  for (int it = 0; it < 15; ++it) {
    gemm64(Zc + mo, nullptr, Yc + mo, nullptr, nullptr,
           W + (size_t)(mat * 2 + sub) * MATF, As, Bs, ti, tj, sub * 256, 256, 0);
    grid.sync();
    const float* Wm0 = W + (size_t)mat * 2 * MATF;
    const float* Wm1 = Wm0 + MATF;
    if (sub == 0) {
      gemm64(Yc + mo, nullptr, Wm0, Wm1, Yc + mo, Yn + mo, As, Bs, ti, tj, 0, 512, 1);
    } else {
      gemm64(Wm0, Wm1, Zc + mo, nullptr, Zc + mo, Zn + mo, As, Bs, ti, tj, 0, 512, 1);
    }
    grid.sync();
    float* tp;
    tp = Yc; Yc = Yn; Yn = tp;
    tp = Zc; Zc = Zn; Zn = tp;
  }

  // cross = sum_ij YA[i,j]*YB[j,i] in fp64
  double cs = 0.0;
#pragma unroll
  for (int c = 0; c < 4; ++c) {
    const int id = c * 65536 + bid * 256 + t;
    const int i = id >> 9, j = id & 511;
    cs += (double)Yc[id] * (double)Yc[MATF + j * 512 + i];
  }
  sm[t] = cs;
  __syncthreads();
  for (int o = 128; o > 0; o >>= 1) {
    if (t < o) sm[t] += sm[t + o];
    __syncthreads();
  }
  if (t == 0) atomicAdd(&S[4], sm[0]);
  grid.sync();

  if (bid == 0) {
    double s = 0.0;
    for (int i = t; i < 512; i += 256) {
      double d = (Msum[i] - Msum[512 + i]) * (1.0 / 65536.0);
      s += d * d;
    }
    sm[t] = s;
    __syncthreads();
    for (int o = 128; o > 0; o >>= 1) {
      if (t < o) sm[t] += sm[t + o];
      __syncthreads();
    }
    if (t == 0) {
      double scale = sqrt(sqrt(S[0]) * sqrt(S[1]));
      double loss = sm[0] + S[2] + S[3] - 2.0 * scale * S[4];
      out[0] = (float)(loss / 512.0);
    }
  }
}

extern "C" void kernel_launch(void* const* d_in, const int* in_sizes, int n_in,
                              void* d_out, int out_size, void* d_ws, size_t ws_size,
                              hipStream_t stream) {
  const float* X = (const float*)d_in[0];
  const float* Xt = (const float*)d_in[1];
  char* wsb = (char*)d_ws;
  double* S = (double*)(wsb + 4096);
  double* Msum = (double*)(wsb + 4096 + 128);
  float* G = (float*)(wsb + 16384);
  float* big = (float*)(wsb + 16384 + 2 * (size_t)MATF * 4);

  // split-K factor: 32 if the workspace can hold 64 MB of partials, else 16
  const int nk = (ws_size >= (size_t)72 * 1024 * 1024) ? 32 : 16;
  const int chunk = KDIM / nk;

  float* Gp = big;                        // dead after k_gfin
  float* Y0 = big;
  float* Z0 = big + 2 * (size_t)MATF;
  float* Y1 = big + 4 * (size_t)MATF;
  float* Z1 = big + 6 * (size_t)MATF;
  float* W  = big + 8 * (size_t)MATF;
  float* outp = (float*)d_out;

  hipMemsetAsync(S, 0, 128 + 8192, stream);   // S[16] + Msum[1024]
  k_gram<<<dim3(10, nk, 2), 256, 0, stream>>>(X, Xt, Gp, Msum, nk, chunk);
  k_gfin<<<dim3(1024, 2), 256, 0, stream>>>(Gp, Msum, G, S, nk);
  void* args[] = {&G, &Msum, &S, &Y0, &Z0, &Y1, &Z1, &W, &outp};
  hipLaunchCooperativeKernel((void*)k_ns_all, dim3(256), dim3(256), args, 0, stream);
}